// Round 1
// baseline (1020.072 us; speedup 1.0000x reference)
//
#include <hip/hip_runtime.h>
#include <hip/hip_bf16.h>

// Problem constants (match reference)
#define NN      65536     // nodes (B * N_PER)
#define EE      524288    // edges (B * E_PER)
#define HIDC    256
#define BB      64
#define EPB     8192      // edges per batch
#define NPB     1024      // nodes per batch
#define NRES    4096      // resolved (causal) edges per batch

// Output region offsets (floats)
#define O_CX    0                      // causal_x      (NN*HIDC)
#define O_CEI   16777216               // causal_ei_rel (2*BB*NRES)
#define O_CW    17301504               // causal_w      (BB*NRES)
#define O_CB    17563648               // causal_batch  (NN)
#define O_FX    17629184               // conf_x        (NN*HIDC)
#define O_FEI   34406400               // conf_ei_rel   (2*BB*NRES)
#define O_FW    34930688               // conf_w        (BB*NRES)
#define O_FB    35192832               // conf_batch    (NN)
#define O_ES    35258368               // edge_score    (EE)

__device__ __forceinline__ unsigned f2ord(float f) {
    unsigned u = __float_as_uint(f);
    return (u & 0x80000000u) ? ~u : (u | 0x80000000u); // monotone ascending map
}

// ---------------- init: zero the flag arrays ----------------
__global__ void k_init(int* __restrict__ flagC, int* __restrict__ flagF) {
    int v = blockIdx.x * blockDim.x + threadIdx.x;
    if (v < NN) { flagC[v] = 0; flagF[v] = 0; }
}

// ---------------- CSR: per-batch stable sort of edges by row ----------------
__global__ __launch_bounds__(1024) void k_sort_csr(const int* __restrict__ row,
                                                   int* __restrict__ sortedKey) {
    __shared__ unsigned lds[EPB];   // 32 KB
    int b = blockIdx.x, t = threadIdx.x;
    int base = b * EPB;
    for (int i = t; i < EPB; i += 1024) {
        int r = row[base + i] & (NPB - 1);
        lds[i] = ((unsigned)r << 13) | (unsigned)i;  // distinct keys -> stable
    }
    __syncthreads();
    for (int k = 2; k <= EPB; k <<= 1) {
        for (int j = k >> 1; j > 0; j >>= 1) {
            for (int t2 = t; t2 < EPB / 2; t2 += 1024) {
                int i = ((t2 & ~(j - 1)) << 1) | (t2 & (j - 1));
                int l = i | j;
                unsigned a = lds[i], c = lds[l];
                bool up = ((i & k) == 0);
                if ((a > c) == up) { lds[i] = c; lds[l] = a; }
            }
            __syncthreads();
        }
    }
    for (int i = t; i < EPB; i += 1024) sortedKey[base + i] = (int)lds[i];
}

__global__ void k_rowptr(const int* __restrict__ sortedKey, int* __restrict__ rowPtr) {
    int v = blockIdx.x * blockDim.x + threadIdx.x;
    if (v >= NN) return;
    int b = v >> 10, r = v & (NPB - 1);
    const int* keys = sortedKey + b * EPB;
    int target = r << 13;
    int lo = 0, hi = EPB;
    while (lo < hi) { int mid = (lo + hi) >> 1; if (keys[mid] < target) lo = mid + 1; else hi = mid; }
    rowPtr[v] = b * EPB + lo;
    if (v == 0) rowPtr[NN] = EE;
}

// ---------------- aggregation: dst[v] = resid[v] + sum_{e in row v} src[col[e]] ----------------
// one wave per node; sequential over edges in ascending global edge index (np.add.at order)
__global__ __launch_bounds__(256) void k_agg(const float* __restrict__ src,
                                             const float* __restrict__ resid,
                                             const int* __restrict__ col,
                                             const int* __restrict__ sortedKey,
                                             const int* __restrict__ rowPtr,
                                             float* __restrict__ dst) {
    int wave = threadIdx.x >> 6, lane = threadIdx.x & 63;
    int v = blockIdx.x * 4 + wave;
    int c0 = lane << 2;
    float4 acc = make_float4(0.f, 0.f, 0.f, 0.f);
    int e0 = rowPtr[v], e1 = rowPtr[v + 1];
    int ebase = (v >> 10) * EPB;
    for (int e = e0; e < e1; ++e) {
        int le = sortedKey[e] & (EPB - 1);
        int c = col[ebase + le];
        float4 sv = *(const float4*)(src + (size_t)c * HIDC + c0);
        acc.x += sv.x; acc.y += sv.y; acc.z += sv.z; acc.w += sv.w;
    }
    float4 rv = *(const float4*)(resid + (size_t)v * HIDC + c0);
    float4 o = make_float4(rv.x + acc.x, rv.y + acc.y, rv.z + acc.z, rv.w + acc.w);
    *(float4*)(dst + (size_t)v * HIDC + c0) = o;
}

// ---------------- fp32 GEMM: C = relu(A @ W + bias), A: NN x 256, W: 256 x 256 ----------------
// 128x128 block tile, 8x8 per thread, BK=16
__global__ __launch_bounds__(256) void k_gemm(const float* __restrict__ A,
                                              const float* __restrict__ W,
                                              const float* __restrict__ bias,
                                              float* __restrict__ C) {
    __shared__ float As[16][132];   // [k][m], padded
    __shared__ float Ws[16][128];   // [k][n]
    int t = threadIdx.x;
    int bm = blockIdx.x * 128;
    int bn = blockIdx.y * 128;
    int tx = t & 15, ty = t >> 4;
    int an0 = tx * 8, am0 = ty * 8;
    float acc[8][8] = {};
    int ar = t >> 1, ak = (t & 1) << 3;
    int wk = t >> 4, wn = (t & 15) << 3;
    const float* Aptr = A + (size_t)(bm + ar) * HIDC + ak;
    const float* Wptr = W + (size_t)wk * HIDC + bn + wn;
    for (int k0 = 0; k0 < HIDC; k0 += 16) {
        float4 a0 = *(const float4*)(Aptr + k0);
        float4 a1 = *(const float4*)(Aptr + k0 + 4);
        float4 w0 = *(const float4*)(Wptr + (size_t)k0 * HIDC);
        float4 w1 = *(const float4*)(Wptr + (size_t)k0 * HIDC + 4);
        __syncthreads();
        As[ak + 0][ar] = a0.x; As[ak + 1][ar] = a0.y; As[ak + 2][ar] = a0.z; As[ak + 3][ar] = a0.w;
        As[ak + 4][ar] = a1.x; As[ak + 5][ar] = a1.y; As[ak + 6][ar] = a1.z; As[ak + 7][ar] = a1.w;
        *(float4*)&Ws[wk][wn] = w0;
        *(float4*)&Ws[wk][wn + 4] = w1;
        __syncthreads();
#pragma unroll
        for (int kk = 0; kk < 16; ++kk) {
            float am[8], wn8[8];
            *(float4*)&am[0]  = *(const float4*)&As[kk][am0];
            *(float4*)&am[4]  = *(const float4*)&As[kk][am0 + 4];
            *(float4*)&wn8[0] = *(const float4*)&Ws[kk][an0];
            *(float4*)&wn8[4] = *(const float4*)&Ws[kk][an0 + 4];
#pragma unroll
            for (int i = 0; i < 8; ++i)
#pragma unroll
                for (int j = 0; j < 8; ++j)
                    acc[i][j] = fmaf(am[i], wn8[j], acc[i][j]);
        }
    }
    float bv[8];
    *(float4*)&bv[0] = *(const float4*)&bias[bn + an0];
    *(float4*)&bv[4] = *(const float4*)&bias[bn + an0 + 4];
#pragma unroll
    for (int i = 0; i < 8; ++i) {
        float o[8];
#pragma unroll
        for (int j = 0; j < 8; ++j) { float x = acc[i][j] + bv[j]; o[j] = x > 0.f ? x : 0.f; }
        float* cp = C + (size_t)(bm + am0 + i) * HIDC + bn + an0;
        *(float4*)cp = *(float4*)&o[0];
        *(float4*)(cp + 4) = *(float4*)&o[4];
    }
}

// ---------------- node scores: s_src = h . w[0:256], s_dst = h . w[256:512] ----------------
__global__ __launch_bounds__(256) void k_score(const float* __restrict__ h,
                                               const float* __restrict__ wsc,
                                               float* __restrict__ sSrc,
                                               float* __restrict__ sDst) {
    int wave = threadIdx.x >> 6, lane = threadIdx.x & 63;
    int v = blockIdx.x * 4 + wave;
    int c0 = lane << 2;
    float4 hv = *(const float4*)(h + (size_t)v * HIDC + c0);
    float4 w0 = *(const float4*)(wsc + c0);
    float4 w1 = *(const float4*)(wsc + HIDC + c0);
    float p0 = (hv.x * w0.x + hv.y * w0.y) + (hv.z * w0.z + hv.w * w0.w);
    float p1 = (hv.x * w1.x + hv.y * w1.y) + (hv.z * w1.z + hv.w * w1.w);
#pragma unroll
    for (int off = 32; off > 0; off >>= 1) {
        p0 += __shfl_down(p0, off, 64);
        p1 += __shfl_down(p1, off, 64);
    }
    if (lane == 0) { sSrc[v] = p0; sDst[v] = p1; }
}

__global__ void k_escore(const int* __restrict__ row, const int* __restrict__ col,
                         const float* __restrict__ sSrc, const float* __restrict__ sDst,
                         const float* __restrict__ bsc, float* __restrict__ out9) {
    int e = blockIdx.x * blockDim.x + threadIdx.x;
    if (e >= EE) return;
    out9[e] = sSrc[row[e]] + sDst[col[e]] + bsc[0];
}

// ---------------- per-batch stable descending argsort of 8192 scores ----------------
__global__ __launch_bounds__(1024) void k_sort_scores(const float* __restrict__ esc,
                                                      int* __restrict__ perm) {
    __shared__ unsigned long long lds[EPB];  // 64 KB
    int b = blockIdx.x, t = threadIdx.x;
    int base = b * EPB;
    for (int i = t; i < EPB; i += 1024) {
        unsigned m = f2ord(esc[base + i]);
        lds[i] = ((unsigned long long)(~m) << 32) | (unsigned)i;  // asc sort == desc score, idx tiebreak
    }
    __syncthreads();
    for (int k = 2; k <= EPB; k <<= 1) {
        for (int j = k >> 1; j > 0; j >>= 1) {
            for (int t2 = t; t2 < EPB / 2; t2 += 1024) {
                int i = ((t2 & ~(j - 1)) << 1) | (t2 & (j - 1));
                int l = i | j;
                unsigned long long a = lds[i], c = lds[l];
                bool up = ((i & k) == 0);
                if ((a > c) == up) { lds[i] = c; lds[l] = a; }
            }
            __syncthreads();
        }
    }
    for (int i = t; i < EPB; i += 1024) perm[base + i] = (int)(lds[i] & 0x1FFFull);
}

// ---------------- flags (node presence per set) + causal_w/conf_w ----------------
__global__ void k_flags(const int* __restrict__ perm, const int* __restrict__ row,
                        const int* __restrict__ col, const float* __restrict__ esc,
                        int* __restrict__ flagC, int* __restrict__ flagF,
                        float* __restrict__ outCW, float* __restrict__ outFW) {
    int g = blockIdx.x * blockDim.x + threadIdx.x;
    if (g >= EE) return;
    int b = g >> 13, jj = g & (EPB - 1);
    int ge = (b << 13) | perm[g];
    int r = row[ge], c = col[ge];
    float s = esc[ge];
    if (jj < NRES) {
        flagC[r] = 1; flagC[c] = 1;
        outCW[b * NRES + jj] = s;
    } else {
        flagF[r] = 1; flagF[c] = 1;
        outFW[b * NRES + (jj - NRES)] = -s;
    }
}

// ---------------- hierarchical exclusive scan over flags (both sets at once) ----------------
__global__ __launch_bounds__(256) void k_scan1(const int* __restrict__ fc, const int* __restrict__ ff,
                                               int* __restrict__ bsC, int* __restrict__ bsF) {
    __shared__ int s1[256], s2[256];
    int t = threadIdx.x, v = blockIdx.x * 256 + t;
    s1[t] = fc[v]; s2[t] = ff[v];
    __syncthreads();
    for (int off = 128; off > 0; off >>= 1) {
        if (t < off) { s1[t] += s1[t + off]; s2[t] += s2[t + off]; }
        __syncthreads();
    }
    if (t == 0) { bsC[blockIdx.x] = s1[0]; bsF[blockIdx.x] = s2[0]; }
}

__global__ __launch_bounds__(256) void k_scan2(const int* __restrict__ bsC, const int* __restrict__ bsF,
                                               int* __restrict__ boC, int* __restrict__ boF,
                                               int* __restrict__ prefC, int* __restrict__ prefF) {
    __shared__ int s1[256], s2[256];
    int t = threadIdx.x;
    int v1 = bsC[t], v2 = bsF[t];
    s1[t] = v1; s2[t] = v2;
    __syncthreads();
    for (int off = 1; off < 256; off <<= 1) {
        int a1 = (t >= off) ? s1[t - off] : 0;
        int a2 = (t >= off) ? s2[t - off] : 0;
        __syncthreads();
        s1[t] += a1; s2[t] += a2;
        __syncthreads();
    }
    boC[t] = s1[t] - v1; boF[t] = s2[t] - v2;
    if (t == 255) { prefC[NN] = s1[255]; prefF[NN] = s2[255]; }
}

__global__ __launch_bounds__(256) void k_scan3(const int* __restrict__ fc, const int* __restrict__ ff,
                                               const int* __restrict__ boC, const int* __restrict__ boF,
                                               int* __restrict__ prefC, int* __restrict__ prefF) {
    __shared__ int s1[256], s2[256];
    int t = threadIdx.x, v = blockIdx.x * 256 + t;
    int f1 = fc[v], f2 = ff[v];
    s1[t] = f1; s2[t] = f2;
    __syncthreads();
    for (int off = 1; off < 256; off <<= 1) {
        int a1 = (t >= off) ? s1[t - off] : 0;
        int a2 = (t >= off) ? s2[t - off] : 0;
        __syncthreads();
        s1[t] += a1; s2[t] += a2;
        __syncthreads();
    }
    prefC[v] = boC[blockIdx.x] + s1[t] - f1;
    prefF[v] = boF[blockIdx.x] + s2[t] - f2;
}

// ---------------- scatter h rows to relabeled positions + pad tail ----------------
__global__ __launch_bounds__(256) void k_scatter(const int* __restrict__ flag, const int* __restrict__ pref,
                                                 const float* __restrict__ h,
                                                 float* __restrict__ outX, float* __restrict__ outB) {
    int wave = threadIdx.x >> 6, lane = threadIdx.x & 63;
    int i = blockIdx.x * 4 + wave;
    int c0 = lane << 2;
    int nu = pref[NN];
    if (flag[i]) {
        int pos = pref[i];
        *(float4*)(outX + (size_t)pos * HIDC + c0) = *(const float4*)(h + (size_t)i * HIDC + c0);
        if (lane == 0) outB[pos] = (float)(i >> 10);
    }
    if (i >= nu) {
        float4 z = make_float4(0.f, 0.f, 0.f, 0.f);
        *(float4*)(outX + (size_t)i * HIDC + c0) = z;
        if (lane == 0) outB[i] = -1.0f;
    }
}

// ---------------- relabeled edge indices (as floats) ----------------
__global__ void k_eirel(const int* __restrict__ perm, const int* __restrict__ row,
                        const int* __restrict__ col, const int* __restrict__ prefC,
                        const int* __restrict__ prefF,
                        float* __restrict__ outC, float* __restrict__ outF) {
    int g = blockIdx.x * blockDim.x + threadIdx.x;
    if (g >= EE) return;
    int b = g >> 13, jj = g & (EPB - 1);
    int ge = (b << 13) | perm[g];
    int r = row[ge], c = col[ge];
    if (jj < NRES) {
        int idx = b * NRES + jj;
        outC[idx] = (float)prefC[r];
        outC[BB * NRES + idx] = (float)prefC[c];
    } else {
        int idx = b * NRES + (jj - NRES);
        outF[idx] = (float)prefF[r];
        outF[BB * NRES + idx] = (float)prefF[c];
    }
}

extern "C" void kernel_launch(void* const* d_in, const int* in_sizes, int n_in,
                              void* d_out, int out_size, void* d_ws, size_t ws_size,
                              hipStream_t stream) {
    const float* x   = (const float*)d_in[0];
    const int*   ei  = (const int*)d_in[1];
    const int*   row = ei;
    const int*   col = ei + EE;
    const float* W11 = (const float*)d_in[3];
    const float* b11 = (const float*)d_in[4];
    const float* W12 = (const float*)d_in[5];
    const float* b12 = (const float*)d_in[6];
    const float* W21 = (const float*)d_in[7];
    const float* b21 = (const float*)d_in[8];
    const float* W22 = (const float*)d_in[9];
    const float* b22 = (const float*)d_in[10];
    const float* wsc = (const float*)d_in[11];
    const float* bsc = (const float*)d_in[12];

    float* out = (float*)d_out;

    // bufA lives in the causal_x output region (dead until final scatter)
    float* bufA = out + O_CX;

    // workspace carve-up (256B aligned regions)
    char* w = (char*)d_ws;
    auto alloc = [&](size_t bytes) { char* p = w; w += (bytes + 255) & ~(size_t)255; return p; };
    float* bufB      = (float*)alloc((size_t)NN * HIDC * 4);
    float* sSrc      = (float*)alloc((size_t)NN * 4);
    float* sDst      = (float*)alloc((size_t)NN * 4);
    int*   sortedKey = (int*)alloc((size_t)EE * 4);
    int*   rowPtr    = (int*)alloc((size_t)(NN + 1) * 4);
    int*   perm      = (int*)alloc((size_t)EE * 4);
    int*   flagC     = (int*)alloc((size_t)NN * 4);
    int*   flagF     = (int*)alloc((size_t)NN * 4);
    int*   prefC     = (int*)alloc((size_t)(NN + 1) * 4);
    int*   prefF     = (int*)alloc((size_t)(NN + 1) * 4);
    int*   bsC       = (int*)alloc(256 * 4);
    int*   bsF       = (int*)alloc(256 * 4);
    int*   boC       = (int*)alloc(256 * 4);
    int*   boF       = (int*)alloc(256 * 4);

    float* esc = out + O_ES;  // edge scores written straight to output region

    hipLaunchKernelGGL(k_init, dim3(NN / 256), dim3(256), 0, stream, flagC, flagF);
    hipLaunchKernelGGL(k_sort_csr, dim3(BB), dim3(1024), 0, stream, row, sortedKey);
    hipLaunchKernelGGL(k_rowptr, dim3(NN / 256), dim3(256), 0, stream, sortedKey, rowPtr);

    // layer 1
    hipLaunchKernelGGL(k_agg, dim3(NN / 4), dim3(256), 0, stream, x, x, col, sortedKey, rowPtr, bufA);
    hipLaunchKernelGGL(k_gemm, dim3(NN / 128, 2), dim3(256), 0, stream, bufA, W11, b11, bufB);
    hipLaunchKernelGGL(k_gemm, dim3(NN / 128, 2), dim3(256), 0, stream, bufB, W12, b12, bufA); // h2
    // layer 2
    hipLaunchKernelGGL(k_agg, dim3(NN / 4), dim3(256), 0, stream, bufA, bufA, col, sortedKey, rowPtr, bufB);
    hipLaunchKernelGGL(k_gemm, dim3(NN / 128, 2), dim3(256), 0, stream, bufB, W21, b21, bufA); // h3
    hipLaunchKernelGGL(k_gemm, dim3(NN / 128, 2), dim3(256), 0, stream, bufA, W22, b22, bufB); // h final

    // scores
    hipLaunchKernelGGL(k_score, dim3(NN / 4), dim3(256), 0, stream, bufB, wsc, sSrc, sDst);
    hipLaunchKernelGGL(k_escore, dim3(EE / 256), dim3(256), 0, stream, row, col, sSrc, sDst, bsc, esc);

    // per-batch argsort + selection
    hipLaunchKernelGGL(k_sort_scores, dim3(BB), dim3(1024), 0, stream, esc, perm);
    hipLaunchKernelGGL(k_flags, dim3(EE / 256), dim3(256), 0, stream, perm, row, col, esc,
                       flagC, flagF, out + O_CW, out + O_FW);

    // prefix sums for relabel
    hipLaunchKernelGGL(k_scan1, dim3(NN / 256), dim3(256), 0, stream, flagC, flagF, bsC, bsF);
    hipLaunchKernelGGL(k_scan2, dim3(1), dim3(256), 0, stream, bsC, bsF, boC, boF, prefC, prefF);
    hipLaunchKernelGGL(k_scan3, dim3(NN / 256), dim3(256), 0, stream, flagC, flagF, boC, boF, prefC, prefF);

    // outputs (causal scatter overwrites bufA region — bufA is dead by now)
    hipLaunchKernelGGL(k_scatter, dim3(NN / 4), dim3(256), 0, stream, flagC, prefC, bufB,
                       out + O_CX, out + O_CB);
    hipLaunchKernelGGL(k_scatter, dim3(NN / 4), dim3(256), 0, stream, flagF, prefF, bufB,
                       out + O_FX, out + O_FB);
    hipLaunchKernelGGL(k_eirel, dim3(EE / 256), dim3(256), 0, stream, perm, row, col,
                       prefC, prefF, out + O_CEI, out + O_FEI);
}

// Round 2
// 714.176 us; speedup vs baseline: 1.4283x; 1.4283x over previous
//
#include <hip/hip_runtime.h>
#include <hip/hip_bf16.h>

// Problem constants (match reference)
#define NN      65536     // nodes (B * N_PER)
#define EE      524288    // edges (B * E_PER)
#define HIDC    256
#define BB      64
#define EPB     8192      // edges per batch
#define NPB     1024      // nodes per batch
#define NRES    4096      // resolved (causal) edges per batch

// Output region offsets (floats)
#define O_CX    0                      // causal_x      (NN*HIDC)
#define O_CEI   16777216               // causal_ei_rel (2*BB*NRES)
#define O_CW    17301504               // causal_w      (BB*NRES)
#define O_CB    17563648               // causal_batch  (NN)
#define O_FX    17629184               // conf_x        (NN*HIDC)
#define O_FEI   34406400               // conf_ei_rel   (2*BB*NRES)
#define O_FW    34930688               // conf_w        (BB*NRES)
#define O_FB    35192832               // conf_batch    (NN)
#define O_ES    35258368               // edge_score    (EE)

typedef __attribute__((ext_vector_type(8))) short short8v;
typedef __attribute__((ext_vector_type(4))) float f32x4;

__device__ __forceinline__ unsigned f2ord(float f) {
    unsigned u = __float_as_uint(f);
    return (u & 0x80000000u) ? ~u : (u | 0x80000000u); // monotone ascending map
}

// split fp32 into hi/lo bf16 (RNE), packed hi<<16 | lo. v = hi + lo + O(2^-17 v)
__device__ __forceinline__ unsigned packsplit(float v) {
    unsigned u = __float_as_uint(v);
    unsigned hi = (u + 0x7FFFu + ((u >> 16) & 1u)) & 0xFFFF0000u;
    float lo = v - __uint_as_float(hi);
    unsigned ul = __float_as_uint(lo);
    unsigned lo16 = (ul + 0x7FFFu + ((ul >> 16) & 1u)) >> 16;
    return hi | lo16;
}

// ---------------- init: zero the flag arrays ----------------
__global__ void k_init(int* __restrict__ flagC, int* __restrict__ flagF) {
    int v = blockIdx.x * blockDim.x + threadIdx.x;
    if (v < NN) { flagC[v] = 0; flagF[v] = 0; }
}

// ---------------- split + transpose the 4 weight matrices ----------------
// Wtp[w][n][k] = packsplit(W_w[k][n])
__global__ void k_wsplit(const float* __restrict__ W11, const float* __restrict__ W12,
                         const float* __restrict__ W21, const float* __restrict__ W22,
                         unsigned* __restrict__ Wtp) {
    int g = blockIdx.x * 256 + threadIdx.x;   // 4*65536 threads
    int w = g >> 16, r = g & 65535;
    int n = r >> 8, k = r & 255;
    const float* W = (w == 0) ? W11 : (w == 1) ? W12 : (w == 2) ? W21 : W22;
    Wtp[g] = packsplit(W[k * 256 + n]);
}

// ---------------- CSR: per-batch stable sort of edges by row ----------------
__global__ __launch_bounds__(1024) void k_sort_csr(const int* __restrict__ row,
                                                   int* __restrict__ sortedKey) {
    __shared__ unsigned lds[EPB];   // 32 KB
    int b = blockIdx.x, t = threadIdx.x;
    int base = b * EPB;
    for (int i = t; i < EPB; i += 1024) {
        int r = row[base + i] & (NPB - 1);
        lds[i] = ((unsigned)r << 13) | (unsigned)i;  // distinct keys -> stable
    }
    __syncthreads();
    for (int k = 2; k <= EPB; k <<= 1) {
        for (int j = k >> 1; j > 0; j >>= 1) {
            for (int t2 = t; t2 < EPB / 2; t2 += 1024) {
                int i = ((t2 & ~(j - 1)) << 1) | (t2 & (j - 1));
                int l = i | j;
                unsigned a = lds[i], c = lds[l];
                bool up = ((i & k) == 0);
                if ((a > c) == up) { lds[i] = c; lds[l] = a; }
            }
            __syncthreads();
        }
    }
    for (int i = t; i < EPB; i += 1024) sortedKey[base + i] = (int)lds[i];
}

__global__ void k_rowptr(const int* __restrict__ sortedKey, int* __restrict__ rowPtr) {
    int v = blockIdx.x * blockDim.x + threadIdx.x;
    if (v >= NN) return;
    int b = v >> 10, r = v & (NPB - 1);
    const int* keys = sortedKey + b * EPB;
    int target = r << 13;
    int lo = 0, hi = EPB;
    while (lo < hi) { int mid = (lo + hi) >> 1; if (keys[mid] < target) lo = mid + 1; else hi = mid; }
    rowPtr[v] = b * EPB + lo;
    if (v == 0) rowPtr[NN] = EE;
}

// colSorted[e] = col of the e-th edge in (row, edge-idx) sorted order
__global__ void k_colgather(const int* __restrict__ sortedKey, const int* __restrict__ col,
                            int* __restrict__ colSorted) {
    int g = blockIdx.x * 256 + threadIdx.x;
    int b = g >> 13;
    int le = sortedKey[g] & (EPB - 1);
    colSorted[g] = col[(b << 13) | le];
}

// ---------------- aggregation: dstP[v] = packsplit(resid[v] + sum_{e in row v} src[col[e]]) ----
// one wave per node; ascending edge order (np.add.at order); index prefetch + shfl broadcast
__global__ __launch_bounds__(256) void k_agg(const float* __restrict__ src,
                                             const float* __restrict__ resid,
                                             const int* __restrict__ colSorted,
                                             const int* __restrict__ rowPtr,
                                             unsigned* __restrict__ dstP) {
    int lane = threadIdx.x & 63;
    int v = blockIdx.x * 4 + (threadIdx.x >> 6);
    int e0 = rowPtr[v], e1 = rowPtr[v + 1];
    int cnt = e1 - e0;
    float4 acc = make_float4(0.f, 0.f, 0.f, 0.f);
    int myc = (lane < cnt) ? colSorted[e0 + lane] : 0;
    int lim = cnt < 64 ? cnt : 64;
    for (int base = 0; base < lim; base += 8) {
        int n = lim - base; if (n > 8) n = 8;
        float4 tv[8];
#pragma unroll
        for (int j = 0; j < 8; ++j)
            if (j < n) {
                int c = __shfl(myc, base + j, 64);
                tv[j] = *((const float4*)src + (size_t)c * 64 + lane);
            }
#pragma unroll
        for (int j = 0; j < 8; ++j)
            if (j < n) { acc.x += tv[j].x; acc.y += tv[j].y; acc.z += tv[j].z; acc.w += tv[j].w; }
    }
    for (int e = e0 + 64; e < e1; ++e) {  // safety tail (cnt>64 is astronomically rare)
        int c = colSorted[e];
        float4 sv = *((const float4*)src + (size_t)c * 64 + lane);
        acc.x += sv.x; acc.y += sv.y; acc.z += sv.z; acc.w += sv.w;
    }
    float4 rv = *((const float4*)resid + (size_t)v * 64 + lane);
    uint4 o;
    o.x = packsplit(rv.x + acc.x);
    o.y = packsplit(rv.y + acc.y);
    o.z = packsplit(rv.z + acc.z);
    o.w = packsplit(rv.w + acc.w);
    *((uint4*)dstP + (size_t)v * 64 + lane) = o;
}

// ---------------- bf16x2 split MFMA GEMM: C = relu(A @ W + bias) ----------------
// A: NN x 256 packed(hi|lo), Wtp: [n][k] packed. 128x128 tile, BK=32 (one MFMA K per stage).
// EPI=0: write packed split (uint); EPI=1: write fp32.
template<int EPI>
__global__ __launch_bounds__(256) void k_gemm_mfma(const unsigned* __restrict__ Ap,
                                                   const unsigned* __restrict__ Wtp,
                                                   const float* __restrict__ bias,
                                                   void* __restrict__ Cout) {
    __shared__ short Ah[128][40];   // stride 40 shorts (80B) breaks pow-2 bank stride
    __shared__ short Al[128][40];
    __shared__ short Bh[128][40];
    __shared__ short Bl[128][40];
    int t = threadIdx.x;
    int lane = t & 63, wave = t >> 6;
    int bm = blockIdx.x * 128, bn = blockIdx.y * 128;
    int ln = lane & 15, qd = lane >> 4;
    f32x4 acc[2][8];
#pragma unroll
    for (int i = 0; i < 2; ++i)
#pragma unroll
        for (int j = 0; j < 8; ++j) acc[i][j] = (f32x4){0.f, 0.f, 0.f, 0.f};
    int row = t >> 1, half = t & 1;
    const uint4* ag = (const uint4*)(Ap + (size_t)(bm + row) * 256) + half * 4;
    const uint4* bg = (const uint4*)(Wtp + (size_t)(bn + row) * 256) + half * 4;
    for (int k0 = 0; k0 < 256; k0 += 32) {
        uint4 av[4], bv[4];
#pragma unroll
        for (int s = 0; s < 4; ++s) { av[s] = ag[s]; bv[s] = bg[s]; }
        ag += 8; bg += 8;
        __syncthreads();
#pragma unroll
        for (int s = 0; s < 4; ++s) {
            int kc = half * 16 + s * 4;
            *(short4*)&Ah[row][kc] = make_short4((short)(av[s].x >> 16), (short)(av[s].y >> 16),
                                                 (short)(av[s].z >> 16), (short)(av[s].w >> 16));
            *(short4*)&Al[row][kc] = make_short4((short)av[s].x, (short)av[s].y,
                                                 (short)av[s].z, (short)av[s].w);
            *(short4*)&Bh[row][kc] = make_short4((short)(bv[s].x >> 16), (short)(bv[s].y >> 16),
                                                 (short)(bv[s].z >> 16), (short)(bv[s].w >> 16));
            *(short4*)&Bl[row][kc] = make_short4((short)bv[s].x, (short)bv[s].y,
                                                 (short)bv[s].z, (short)bv[s].w);
        }
        __syncthreads();
        // A-frag: m = lane&15, k = (lane>>4)*8 + j ; B-frag: n = lane&15, k = (lane>>4)*8 + j
        short8v ah0 = *(short8v*)&Ah[wave * 32 + ln][qd * 8];
        short8v ah1 = *(short8v*)&Ah[wave * 32 + 16 + ln][qd * 8];
        short8v al0 = *(short8v*)&Al[wave * 32 + ln][qd * 8];
        short8v al1 = *(short8v*)&Al[wave * 32 + 16 + ln][qd * 8];
#pragma unroll
        for (int nt = 0; nt < 8; ++nt) {
            short8v bh = *(short8v*)&Bh[nt * 16 + ln][qd * 8];
            short8v bl = *(short8v*)&Bl[nt * 16 + ln][qd * 8];
            f32x4 c0 = acc[0][nt];
            c0 = __builtin_amdgcn_mfma_f32_16x16x32_bf16(al0, bl, c0, 0, 0, 0);
            c0 = __builtin_amdgcn_mfma_f32_16x16x32_bf16(al0, bh, c0, 0, 0, 0);
            c0 = __builtin_amdgcn_mfma_f32_16x16x32_bf16(ah0, bl, c0, 0, 0, 0);
            c0 = __builtin_amdgcn_mfma_f32_16x16x32_bf16(ah0, bh, c0, 0, 0, 0);
            acc[0][nt] = c0;
            f32x4 c1 = acc[1][nt];
            c1 = __builtin_amdgcn_mfma_f32_16x16x32_bf16(al1, bl, c1, 0, 0, 0);
            c1 = __builtin_amdgcn_mfma_f32_16x16x32_bf16(al1, bh, c1, 0, 0, 0);
            c1 = __builtin_amdgcn_mfma_f32_16x16x32_bf16(ah1, bl, c1, 0, 0, 0);
            c1 = __builtin_amdgcn_mfma_f32_16x16x32_bf16(ah1, bh, c1, 0, 0, 0);
            acc[1][nt] = c1;
        }
    }
    // epilogue: C/D layout col = lane&15, row = (lane>>4)*4 + reg
#pragma unroll
    for (int nt = 0; nt < 8; ++nt) {
        float bvs = bias[bn + nt * 16 + ln];
#pragma unroll
        for (int mt = 0; mt < 2; ++mt)
#pragma unroll
            for (int r = 0; r < 4; ++r) {
                int gm = bm + wave * 32 + mt * 16 + qd * 4 + r;
                int gn = bn + nt * 16 + ln;
                float v = acc[mt][nt][r] + bvs;
                v = v > 0.f ? v : 0.f;
                if (EPI == 0) ((unsigned*)Cout)[(size_t)gm * 256 + gn] = packsplit(v);
                else          ((float*)Cout)[(size_t)gm * 256 + gn] = v;
            }
    }
}

// ---------------- node scores: s_src = h . w[0:256], s_dst = h . w[256:512] ----------------
__global__ __launch_bounds__(256) void k_score(const float* __restrict__ h,
                                               const float* __restrict__ wsc,
                                               float* __restrict__ sSrc,
                                               float* __restrict__ sDst) {
    int wave = threadIdx.x >> 6, lane = threadIdx.x & 63;
    int v = blockIdx.x * 4 + wave;
    int c0 = lane << 2;
    float4 hv = *(const float4*)(h + (size_t)v * HIDC + c0);
    float4 w0 = *(const float4*)(wsc + c0);
    float4 w1 = *(const float4*)(wsc + HIDC + c0);
    float p0 = (hv.x * w0.x + hv.y * w0.y) + (hv.z * w0.z + hv.w * w0.w);
    float p1 = (hv.x * w1.x + hv.y * w1.y) + (hv.z * w1.z + hv.w * w1.w);
#pragma unroll
    for (int off = 32; off > 0; off >>= 1) {
        p0 += __shfl_down(p0, off, 64);
        p1 += __shfl_down(p1, off, 64);
    }
    if (lane == 0) { sSrc[v] = p0; sDst[v] = p1; }
}

__global__ void k_escore(const int* __restrict__ row, const int* __restrict__ col,
                         const float* __restrict__ sSrc, const float* __restrict__ sDst,
                         const float* __restrict__ bsc, float* __restrict__ out9) {
    int e = blockIdx.x * blockDim.x + threadIdx.x;
    if (e >= EE) return;
    out9[e] = sSrc[row[e]] + sDst[col[e]] + bsc[0];
}

// ---------------- per-batch stable descending argsort of 8192 scores ----------------
__global__ __launch_bounds__(1024) void k_sort_scores(const float* __restrict__ esc,
                                                      int* __restrict__ perm) {
    __shared__ unsigned long long lds[EPB];  // 64 KB
    int b = blockIdx.x, t = threadIdx.x;
    int base = b * EPB;
    for (int i = t; i < EPB; i += 1024) {
        unsigned m = f2ord(esc[base + i]);
        lds[i] = ((unsigned long long)(~m) << 32) | (unsigned)i;  // asc sort == desc score, idx tiebreak
    }
    __syncthreads();
    for (int k = 2; k <= EPB; k <<= 1) {
        for (int j = k >> 1; j > 0; j >>= 1) {
            for (int t2 = t; t2 < EPB / 2; t2 += 1024) {
                int i = ((t2 & ~(j - 1)) << 1) | (t2 & (j - 1));
                int l = i | j;
                unsigned long long a = lds[i], c = lds[l];
                bool up = ((i & k) == 0);
                if ((a > c) == up) { lds[i] = c; lds[l] = a; }
            }
            __syncthreads();
        }
    }
    for (int i = t; i < EPB; i += 1024) perm[base + i] = (int)(lds[i] & 0x1FFFull);
}

// ---------------- flags (node presence per set) + causal_w/conf_w ----------------
__global__ void k_flags(const int* __restrict__ perm, const int* __restrict__ row,
                        const int* __restrict__ col, const float* __restrict__ esc,
                        int* __restrict__ flagC, int* __restrict__ flagF,
                        float* __restrict__ outCW, float* __restrict__ outFW) {
    int g = blockIdx.x * blockDim.x + threadIdx.x;
    if (g >= EE) return;
    int b = g >> 13, jj = g & (EPB - 1);
    int ge = (b << 13) | perm[g];
    int r = row[ge], c = col[ge];
    float s = esc[ge];
    if (jj < NRES) {
        flagC[r] = 1; flagC[c] = 1;
        outCW[b * NRES + jj] = s;
    } else {
        flagF[r] = 1; flagF[c] = 1;
        outFW[b * NRES + (jj - NRES)] = -s;
    }
}

// ---------------- hierarchical exclusive scan over flags (both sets at once) ----------------
__global__ __launch_bounds__(256) void k_scan1(const int* __restrict__ fc, const int* __restrict__ ff,
                                               int* __restrict__ bsC, int* __restrict__ bsF) {
    __shared__ int s1[256], s2[256];
    int t = threadIdx.x, v = blockIdx.x * 256 + t;
    s1[t] = fc[v]; s2[t] = ff[v];
    __syncthreads();
    for (int off = 128; off > 0; off >>= 1) {
        if (t < off) { s1[t] += s1[t + off]; s2[t] += s2[t + off]; }
        __syncthreads();
    }
    if (t == 0) { bsC[blockIdx.x] = s1[0]; bsF[blockIdx.x] = s2[0]; }
}

__global__ __launch_bounds__(256) void k_scan2(const int* __restrict__ bsC, const int* __restrict__ bsF,
                                               int* __restrict__ boC, int* __restrict__ boF,
                                               int* __restrict__ prefC, int* __restrict__ prefF) {
    __shared__ int s1[256], s2[256];
    int t = threadIdx.x;
    int v1 = bsC[t], v2 = bsF[t];
    s1[t] = v1; s2[t] = v2;
    __syncthreads();
    for (int off = 1; off < 256; off <<= 1) {
        int a1 = (t >= off) ? s1[t - off] : 0;
        int a2 = (t >= off) ? s2[t - off] : 0;
        __syncthreads();
        s1[t] += a1; s2[t] += a2;
        __syncthreads();
    }
    boC[t] = s1[t] - v1; boF[t] = s2[t] - v2;
    if (t == 255) { prefC[NN] = s1[255]; prefF[NN] = s2[255]; }
}

__global__ __launch_bounds__(256) void k_scan3(const int* __restrict__ fc, const int* __restrict__ ff,
                                               const int* __restrict__ boC, const int* __restrict__ boF,
                                               int* __restrict__ prefC, int* __restrict__ prefF) {
    __shared__ int s1[256], s2[256];
    int t = threadIdx.x, v = blockIdx.x * 256 + t;
    int f1 = fc[v], f2 = ff[v];
    s1[t] = f1; s2[t] = f2;
    __syncthreads();
    for (int off = 1; off < 256; off <<= 1) {
        int a1 = (t >= off) ? s1[t - off] : 0;
        int a2 = (t >= off) ? s2[t - off] : 0;
        __syncthreads();
        s1[t] += a1; s2[t] += a2;
        __syncthreads();
    }
    prefC[v] = boC[blockIdx.x] + s1[t] - f1;
    prefF[v] = boF[blockIdx.x] + s2[t] - f2;
}

// ---------------- scatter h rows to relabeled positions + pad tail ----------------
__global__ __launch_bounds__(256) void k_scatter(const int* __restrict__ flag, const int* __restrict__ pref,
                                                 const float* __restrict__ h,
                                                 float* __restrict__ outX, float* __restrict__ outB) {
    int wave = threadIdx.x >> 6, lane = threadIdx.x & 63;
    int i = blockIdx.x * 4 + wave;
    int c0 = lane << 2;
    int nu = pref[NN];
    if (flag[i]) {
        int pos = pref[i];
        *(float4*)(outX + (size_t)pos * HIDC + c0) = *(const float4*)(h + (size_t)i * HIDC + c0);
        if (lane == 0) outB[pos] = (float)(i >> 10);
    }
    if (i >= nu) {
        float4 z = make_float4(0.f, 0.f, 0.f, 0.f);
        *(float4*)(outX + (size_t)i * HIDC + c0) = z;
        if (lane == 0) outB[i] = -1.0f;
    }
}

// ---------------- relabeled edge indices (as floats) ----------------
__global__ void k_eirel(const int* __restrict__ perm, const int* __restrict__ row,
                        const int* __restrict__ col, const int* __restrict__ prefC,
                        const int* __restrict__ prefF,
                        float* __restrict__ outC, float* __restrict__ outF) {
    int g = blockIdx.x * blockDim.x + threadIdx.x;
    if (g >= EE) return;
    int b = g >> 13, jj = g & (EPB - 1);
    int ge = (b << 13) | perm[g];
    int r = row[ge], c = col[ge];
    if (jj < NRES) {
        int idx = b * NRES + jj;
        outC[idx] = (float)prefC[r];
        outC[BB * NRES + idx] = (float)prefC[c];
    } else {
        int idx = b * NRES + (jj - NRES);
        outF[idx] = (float)prefF[r];
        outF[BB * NRES + idx] = (float)prefF[c];
    }
}

extern "C" void kernel_launch(void* const* d_in, const int* in_sizes, int n_in,
                              void* d_out, int out_size, void* d_ws, size_t ws_size,
                              hipStream_t stream) {
    const float* x   = (const float*)d_in[0];
    const int*   ei  = (const int*)d_in[1];
    const int*   row = ei;
    const int*   col = ei + EE;
    const float* W11 = (const float*)d_in[3];
    const float* b11 = (const float*)d_in[4];
    const float* W12 = (const float*)d_in[5];
    const float* b12 = (const float*)d_in[6];
    const float* W21 = (const float*)d_in[7];
    const float* b21 = (const float*)d_in[8];
    const float* W22 = (const float*)d_in[9];
    const float* b22 = (const float*)d_in[10];
    const float* wsc = (const float*)d_in[11];
    const float* bsc = (const float*)d_in[12];

    float* out = (float*)d_out;

    // X buffer = causal_x output region (dead until final scatter)
    // usage: a1p (packed) -> h2 (fp32) -> h3p (packed)
    void* X = (void*)(out + O_CX);

    // workspace carve-up (256B aligned regions)
    char* w = (char*)d_ws;
    auto alloc = [&](size_t bytes) { char* p = w; w += (bytes + 255) & ~(size_t)255; return p; };
    void*  P         = (void*)alloc((size_t)NN * HIDC * 4);  // h1p -> a2p -> h (fp32)
    float* sSrc      = (float*)alloc((size_t)NN * 4);
    float* sDst      = (float*)alloc((size_t)NN * 4);
    int*   sortedKey = (int*)alloc((size_t)EE * 4);
    int*   colSorted = (int*)alloc((size_t)EE * 4);
    int*   rowPtr    = (int*)alloc((size_t)(NN + 1) * 4);
    int*   perm      = (int*)alloc((size_t)EE * 4);
    int*   flagC     = (int*)alloc((size_t)NN * 4);
    int*   flagF     = (int*)alloc((size_t)NN * 4);
    int*   prefC     = (int*)alloc((size_t)(NN + 1) * 4);
    int*   prefF     = (int*)alloc((size_t)(NN + 1) * 4);
    unsigned* Wtp    = (unsigned*)alloc((size_t)4 * 65536 * 4);
    int*   bsC       = (int*)alloc(256 * 4);
    int*   bsF       = (int*)alloc(256 * 4);
    int*   boC       = (int*)alloc(256 * 4);
    int*   boF       = (int*)alloc(256 * 4);

    float* esc = out + O_ES;  // edge scores written straight to output region

    hipLaunchKernelGGL(k_init, dim3(NN / 256), dim3(256), 0, stream, flagC, flagF);
    hipLaunchKernelGGL(k_wsplit, dim3(1024), dim3(256), 0, stream, W11, W12, W21, W22, Wtp);
    hipLaunchKernelGGL(k_sort_csr, dim3(BB), dim3(1024), 0, stream, row, sortedKey);
    hipLaunchKernelGGL(k_rowptr, dim3(NN / 256), dim3(256), 0, stream, sortedKey, rowPtr);
    hipLaunchKernelGGL(k_colgather, dim3(EE / 256), dim3(256), 0, stream, sortedKey, col, colSorted);

    dim3 ggrid(NN / 128, 2), gblk(256);

    // layer 1
    hipLaunchKernelGGL(k_agg, dim3(NN / 4), dim3(256), 0, stream, x, x, colSorted, rowPtr, (unsigned*)X);
    k_gemm_mfma<0><<<ggrid, gblk, 0, stream>>>((const unsigned*)X, Wtp + 0 * 65536, b11, P);       // h1p
    k_gemm_mfma<1><<<ggrid, gblk, 0, stream>>>((const unsigned*)P, Wtp + 1 * 65536, b12, X);       // h2 fp32
    // layer 2
    hipLaunchKernelGGL(k_agg, dim3(NN / 4), dim3(256), 0, stream, (const float*)X, (const float*)X,
                       colSorted, rowPtr, (unsigned*)P);                                            // a2p
    k_gemm_mfma<0><<<ggrid, gblk, 0, stream>>>((const unsigned*)P, Wtp + 2 * 65536, b21, X);       // h3p
    k_gemm_mfma<1><<<ggrid, gblk, 0, stream>>>((const unsigned*)X, Wtp + 3 * 65536, b22, P);       // h fp32

    const float* h = (const float*)P;

    // scores
    hipLaunchKernelGGL(k_score, dim3(NN / 4), dim3(256), 0, stream, h, wsc, sSrc, sDst);
    hipLaunchKernelGGL(k_escore, dim3(EE / 256), dim3(256), 0, stream, row, col, sSrc, sDst, bsc, esc);

    // per-batch argsort + selection
    hipLaunchKernelGGL(k_sort_scores, dim3(BB), dim3(1024), 0, stream, esc, perm);
    hipLaunchKernelGGL(k_flags, dim3(EE / 256), dim3(256), 0, stream, perm, row, col, esc,
                       flagC, flagF, out + O_CW, out + O_FW);

    // prefix sums for relabel
    hipLaunchKernelGGL(k_scan1, dim3(NN / 256), dim3(256), 0, stream, flagC, flagF, bsC, bsF);
    hipLaunchKernelGGL(k_scan2, dim3(1), dim3(256), 0, stream, bsC, bsF, boC, boF, prefC, prefF);
    hipLaunchKernelGGL(k_scan3, dim3(NN / 256), dim3(256), 0, stream, flagC, flagF, boC, boF, prefC, prefF);

    // outputs (causal scatter overwrites X region — X is dead by now)
    hipLaunchKernelGGL(k_scatter, dim3(NN / 4), dim3(256), 0, stream, flagC, prefC, h,
                       out + O_CX, out + O_CB);
    hipLaunchKernelGGL(k_scatter, dim3(NN / 4), dim3(256), 0, stream, flagF, prefF, h,
                       out + O_FX, out + O_FB);
    hipLaunchKernelGGL(k_eirel, dim3(EE / 256), dim3(256), 0, stream, perm, row, col,
                       prefC, prefF, out + O_CEI, out + O_FEI);
}

// Round 3
// 622.730 us; speedup vs baseline: 1.6381x; 1.1468x over previous
//
#include <hip/hip_runtime.h>
#include <hip/hip_bf16.h>

// Problem constants (match reference)
#define NN      65536     // nodes (B * N_PER)
#define EE      524288    // edges (B * E_PER)
#define HIDC    256
#define BB      64
#define EPB     8192      // edges per batch
#define NPB     1024      // nodes per batch
#define NRES    4096      // resolved (causal) edges per batch

// Output region offsets (floats)
#define O_CX    0                      // causal_x      (NN*HIDC)
#define O_CEI   16777216               // causal_ei_rel (2*BB*NRES)
#define O_CW    17301504               // causal_w      (BB*NRES)
#define O_CB    17563648               // causal_batch  (NN)
#define O_FX    17629184               // conf_x        (NN*HIDC)
#define O_FEI   34406400               // conf_ei_rel   (2*BB*NRES)
#define O_FW    34930688               // conf_w        (BB*NRES)
#define O_FB    35192832               // conf_batch    (NN)
#define O_ES    35258368               // edge_score    (EE)

typedef __attribute__((ext_vector_type(8))) short short8v;
typedef __attribute__((ext_vector_type(4))) float f32x4;

__device__ __forceinline__ unsigned f2ord(float f) {
    unsigned u = __float_as_uint(f);
    return (u & 0x80000000u) ? ~u : (u | 0x80000000u); // monotone ascending map
}

// split fp32 into hi/lo bf16 (RNE), packed hi<<16 | lo. v = hi + lo + O(2^-17 v)
__device__ __forceinline__ unsigned packsplit(float v) {
    unsigned u = __float_as_uint(v);
    unsigned hi = (u + 0x7FFFu + ((u >> 16) & 1u)) & 0xFFFF0000u;
    float lo = v - __uint_as_float(hi);
    unsigned ul = __float_as_uint(lo);
    unsigned lo16 = (ul + 0x7FFFu + ((ul >> 16) & 1u)) >> 16;
    return hi | lo16;
}

// ---------------- init: zero flags + score accumulators ----------------
__global__ void k_init(int* __restrict__ flagC, int* __restrict__ flagF,
                       float* __restrict__ sSrc, float* __restrict__ sDst) {
    int v = blockIdx.x * blockDim.x + threadIdx.x;
    if (v < NN) { flagC[v] = 0; flagF[v] = 0; sSrc[v] = 0.f; sDst[v] = 0.f; }
}

// ---------------- split + transpose the 4 weight matrices ----------------
// Wtp[w][n][k] = packsplit(W_w[k][n])
__global__ void k_wsplit(const float* __restrict__ W11, const float* __restrict__ W12,
                         const float* __restrict__ W21, const float* __restrict__ W22,
                         unsigned* __restrict__ Wtp) {
    int g = blockIdx.x * 256 + threadIdx.x;   // 4*65536 threads
    int w = g >> 16, r = g & 65535;
    int n = r >> 8, k = r & 255;
    const float* W = (w == 0) ? W11 : (w == 1) ? W12 : (w == 2) ? W21 : W22;
    Wtp[g] = packsplit(W[k * 256 + n]);
}

// ---------------- CSR via per-batch counting sort ----------------
// within-row edge order is arbitrary (only perturbs fp-add order ~1e-7 — harmless)
__global__ __launch_bounds__(1024) void k_csr(const int* __restrict__ row,
                                              const int* __restrict__ col,
                                              int* __restrict__ rowPtr,
                                              int* __restrict__ colSorted) {
    __shared__ int hist[NPB];
    __shared__ int scn[NPB];
    int b = blockIdx.x, t = threadIdx.x;
    int base = b * EPB;
    hist[t] = 0;
    __syncthreads();
    int r[8], c[8];
#pragma unroll
    for (int j = 0; j < 8; ++j) {
        int e = base + t + j * 1024;
        r[j] = row[e] & (NPB - 1);
        c[j] = col[e];
        atomicAdd(&hist[r[j]], 1);
    }
    __syncthreads();
    int v = hist[t];
    scn[t] = v;
    __syncthreads();
    for (int off = 1; off < 1024; off <<= 1) {
        int a = (t >= off) ? scn[t - off] : 0;
        __syncthreads();
        scn[t] += a;
        __syncthreads();
    }
    int start = scn[t] - v;   // exclusive
    rowPtr[b * NPB + t] = base + start;
    if (b == 0 && t == 0) rowPtr[NN] = EE;
    hist[t] = start;          // reuse as cursor
    __syncthreads();
#pragma unroll
    for (int j = 0; j < 8; ++j) {
        int pos = atomicAdd(&hist[r[j]], 1);
        colSorted[base + pos] = c[j];
    }
}

// ---------------- aggregation: dstP[v] = packsplit(resid[v] + sum_{e in row v} src[col[e]]) ----
__global__ __launch_bounds__(256) void k_agg(const float* __restrict__ src,
                                             const float* __restrict__ resid,
                                             const int* __restrict__ colSorted,
                                             const int* __restrict__ rowPtr,
                                             unsigned* __restrict__ dstP) {
    int lane = threadIdx.x & 63;
    int v = blockIdx.x * 4 + (threadIdx.x >> 6);
    int e0 = rowPtr[v], e1 = rowPtr[v + 1];
    int cnt = e1 - e0;
    float4 acc = make_float4(0.f, 0.f, 0.f, 0.f);
    int myc = (lane < cnt) ? colSorted[e0 + lane] : 0;
    int lim = cnt < 64 ? cnt : 64;
    for (int base = 0; base < lim; base += 8) {
        int n = lim - base; if (n > 8) n = 8;
        float4 tv[8];
#pragma unroll
        for (int j = 0; j < 8; ++j)
            if (j < n) {
                int c = __shfl(myc, base + j, 64);
                tv[j] = *((const float4*)src + (size_t)c * 64 + lane);
            }
#pragma unroll
        for (int j = 0; j < 8; ++j)
            if (j < n) { acc.x += tv[j].x; acc.y += tv[j].y; acc.z += tv[j].z; acc.w += tv[j].w; }
    }
    for (int e = e0 + 64; e < e1; ++e) {  // safety tail
        int c = colSorted[e];
        float4 sv = *((const float4*)src + (size_t)c * 64 + lane);
        acc.x += sv.x; acc.y += sv.y; acc.z += sv.z; acc.w += sv.w;
    }
    float4 rv = *((const float4*)resid + (size_t)v * 64 + lane);
    uint4 o;
    o.x = packsplit(rv.x + acc.x);
    o.y = packsplit(rv.y + acc.y);
    o.z = packsplit(rv.z + acc.z);
    o.w = packsplit(rv.w + acc.w);
    *((uint4*)dstP + (size_t)v * 64 + lane) = o;
}

// ---------------- bf16x2 split MFMA GEMM: C = relu(A @ W + bias) ----------------
// 3-term split (drop lo*lo, ~2^-16 rel): C = Al*Bh + Ah*Bl + Ah*Bh
// EPI=0: write packed split; EPI=1: write fp32. SC=1: fused score partial dots (atomicAdd).
template<int EPI, int SC>
__global__ __launch_bounds__(256) void k_gemm_mfma(const unsigned* __restrict__ Ap,
                                                   const unsigned* __restrict__ Wtp,
                                                   const float* __restrict__ bias,
                                                   void* __restrict__ Cout,
                                                   const float* __restrict__ wsc,
                                                   float* __restrict__ sSrc,
                                                   float* __restrict__ sDst) {
    __shared__ short Ah[128][40];   // stride 40 shorts (80B) breaks pow-2 bank stride
    __shared__ short Al[128][40];
    __shared__ short Bh[128][40];
    __shared__ short Bl[128][40];
    int t = threadIdx.x;
    int lane = t & 63, wave = t >> 6;
    int bm = blockIdx.x * 128, bn = blockIdx.y * 128;
    int ln = lane & 15, qd = lane >> 4;
    f32x4 acc[2][8];
#pragma unroll
    for (int i = 0; i < 2; ++i)
#pragma unroll
        for (int j = 0; j < 8; ++j) acc[i][j] = (f32x4){0.f, 0.f, 0.f, 0.f};
    int row = t >> 1, half = t & 1;
    const uint4* ag = (const uint4*)(Ap + (size_t)(bm + row) * 256) + half * 4;
    const uint4* bg = (const uint4*)(Wtp + (size_t)(bn + row) * 256) + half * 4;
    for (int k0 = 0; k0 < 256; k0 += 32) {
        uint4 av[4], bv[4];
#pragma unroll
        for (int s = 0; s < 4; ++s) { av[s] = ag[s]; bv[s] = bg[s]; }
        ag += 8; bg += 8;
        __syncthreads();
#pragma unroll
        for (int s = 0; s < 4; ++s) {
            int kc = half * 16 + s * 4;
            *(short4*)&Ah[row][kc] = make_short4((short)(av[s].x >> 16), (short)(av[s].y >> 16),
                                                 (short)(av[s].z >> 16), (short)(av[s].w >> 16));
            *(short4*)&Al[row][kc] = make_short4((short)av[s].x, (short)av[s].y,
                                                 (short)av[s].z, (short)av[s].w);
            *(short4*)&Bh[row][kc] = make_short4((short)(bv[s].x >> 16), (short)(bv[s].y >> 16),
                                                 (short)(bv[s].z >> 16), (short)(bv[s].w >> 16));
            *(short4*)&Bl[row][kc] = make_short4((short)bv[s].x, (short)bv[s].y,
                                                 (short)bv[s].z, (short)bv[s].w);
        }
        __syncthreads();
        short8v ah0 = *(short8v*)&Ah[wave * 32 + ln][qd * 8];
        short8v ah1 = *(short8v*)&Ah[wave * 32 + 16 + ln][qd * 8];
        short8v al0 = *(short8v*)&Al[wave * 32 + ln][qd * 8];
        short8v al1 = *(short8v*)&Al[wave * 32 + 16 + ln][qd * 8];
#pragma unroll
        for (int nt = 0; nt < 8; ++nt) {
            short8v bh = *(short8v*)&Bh[nt * 16 + ln][qd * 8];
            short8v bl = *(short8v*)&Bl[nt * 16 + ln][qd * 8];
            f32x4 c0 = acc[0][nt];
            c0 = __builtin_amdgcn_mfma_f32_16x16x32_bf16(al0, bh, c0, 0, 0, 0);
            c0 = __builtin_amdgcn_mfma_f32_16x16x32_bf16(ah0, bl, c0, 0, 0, 0);
            c0 = __builtin_amdgcn_mfma_f32_16x16x32_bf16(ah0, bh, c0, 0, 0, 0);
            acc[0][nt] = c0;
            f32x4 c1 = acc[1][nt];
            c1 = __builtin_amdgcn_mfma_f32_16x16x32_bf16(al1, bh, c1, 0, 0, 0);
            c1 = __builtin_amdgcn_mfma_f32_16x16x32_bf16(ah1, bl, c1, 0, 0, 0);
            c1 = __builtin_amdgcn_mfma_f32_16x16x32_bf16(ah1, bh, c1, 0, 0, 0);
            acc[1][nt] = c1;
        }
    }
    // epilogue: C/D layout col = lane&15, row = (lane>>4)*4 + reg
    float ps[2][4] = {}, pd[2][4] = {};
#pragma unroll
    for (int nt = 0; nt < 8; ++nt) {
        float bvs = bias[bn + nt * 16 + ln];
        float ws = 0.f, wd = 0.f;
        if (SC) { ws = wsc[bn + nt * 16 + ln]; wd = wsc[256 + bn + nt * 16 + ln]; }
#pragma unroll
        for (int mt = 0; mt < 2; ++mt)
#pragma unroll
            for (int r = 0; r < 4; ++r) {
                int gm = bm + wave * 32 + mt * 16 + qd * 4 + r;
                int gn = bn + nt * 16 + ln;
                float v = acc[mt][nt][r] + bvs;
                v = v > 0.f ? v : 0.f;
                if (SC) { ps[mt][r] += v * ws; pd[mt][r] += v * wd; }
                if (EPI == 0) ((unsigned*)Cout)[(size_t)gm * 256 + gn] = packsplit(v);
                else          ((float*)Cout)[(size_t)gm * 256 + gn] = v;
            }
    }
    if (SC) {
        // reduce partials across the 16 lanes (ln) sharing each row
#pragma unroll
        for (int off = 1; off < 16; off <<= 1)
#pragma unroll
            for (int mt = 0; mt < 2; ++mt)
#pragma unroll
                for (int r = 0; r < 4; ++r) {
                    ps[mt][r] += __shfl_xor(ps[mt][r], off, 64);
                    pd[mt][r] += __shfl_xor(pd[mt][r], off, 64);
                }
        if (ln == 0) {
#pragma unroll
            for (int mt = 0; mt < 2; ++mt)
#pragma unroll
                for (int r = 0; r < 4; ++r) {
                    int gm = bm + wave * 32 + mt * 16 + qd * 4 + r;
                    atomicAdd(&sSrc[gm], ps[mt][r]);   // exactly 2 addends (grid.y=2): commutative => deterministic
                    atomicAdd(&sDst[gm], pd[mt][r]);
                }
        }
    }
}

__global__ void k_escore(const int* __restrict__ row, const int* __restrict__ col,
                         const float* __restrict__ sSrc, const float* __restrict__ sDst,
                         const float* __restrict__ bsc, float* __restrict__ out9) {
    int e = blockIdx.x * blockDim.x + threadIdx.x;
    if (e >= EE) return;
    out9[e] = sSrc[row[e]] + sDst[col[e]] + bsc[0];
}

// ---------------- hybrid per-batch stable descending argsort (3 phases) ----------------
// S1: sort 4096-chunks (chunk0 asc, chunk1 desc) -> batch sequence is bitonic
__global__ __launch_bounds__(512) void k_sortS1(const float* __restrict__ esc,
                                                unsigned long long* __restrict__ keys) {
    __shared__ unsigned long long lds[4096];  // 32 KB
    int blk = blockIdx.x, b = blk >> 1, c = blk & 1;
    int t = threadIdx.x;
    int gbase = b * EPB + c * 4096;
    for (int i = t; i < 4096; i += 512) {
        int idx = c * 4096 + i;
        unsigned m = f2ord(esc[b * EPB + idx]);
        lds[i] = ((unsigned long long)(~m) << 32) | (unsigned)idx;  // asc == desc score, idx tiebreak
    }
    __syncthreads();
    bool dirbit = (c != 0);
    for (int k = 2; k <= 4096; k <<= 1) {
        for (int j = k >> 1; j > 0; j >>= 1) {
            for (int t2 = t; t2 < 2048; t2 += 512) {
                int i = ((t2 & ~(j - 1)) << 1) | (t2 & (j - 1));
                int l = i | j;
                unsigned long long a = lds[i], d = lds[l];
                bool up = (((i & k) == 0) != dirbit);
                if ((a > d) == up) { lds[i] = d; lds[l] = a; }
            }
            __syncthreads();
        }
    }
    for (int i = t; i < 4096; i += 512) keys[gbase + i] = lds[i];
}

// S2: global pass k=8192, j=4096 (ascending)
__global__ void k_sortS2(unsigned long long* __restrict__ keys) {
    int g = blockIdx.x * 256 + threadIdx.x;   // EE/2 threads
    int b = g >> 12, i = g & 4095;
    unsigned long long* p = keys + b * EPB;
    unsigned long long a = p[i], d = p[i + 4096];
    if (a > d) { p[i] = d; p[i + 4096] = a; }
}

// S3: local merge j=2048..1 + fused flags/perm/causal_w/conf_w epilogue
__global__ __launch_bounds__(512) void k_sortS3(const unsigned long long* __restrict__ keys,
                                                const int* __restrict__ row, const int* __restrict__ col,
                                                const float* __restrict__ esc,
                                                int* __restrict__ perm,
                                                int* __restrict__ flagC, int* __restrict__ flagF,
                                                float* __restrict__ outCW, float* __restrict__ outFW) {
    __shared__ unsigned long long lds[4096];
    int blk = blockIdx.x, b = blk >> 1, c = blk & 1;
    int gbase = b * EPB + c * 4096;
    int t = threadIdx.x;
    for (int i = t; i < 4096; i += 512) lds[i] = keys[gbase + i];
    __syncthreads();
    for (int j = 2048; j > 0; j >>= 1) {
        for (int t2 = t; t2 < 2048; t2 += 512) {
            int i = ((t2 & ~(j - 1)) << 1) | (t2 & (j - 1));
            int l = i | j;
            unsigned long long a = lds[i], d = lds[l];
            if (a > d) { lds[i] = d; lds[l] = a; }  // ascending
        }
        __syncthreads();
    }
    for (int i = t; i < 4096; i += 512) {
        int idx = (int)(lds[i] & 0x1FFFull);
        int ge = b * EPB + idx;
        perm[gbase + i] = idx;
        int r = row[ge], cl = col[ge];
        float s = esc[ge];
        if (c == 0) { flagC[r] = 1; flagC[cl] = 1; outCW[b * NRES + i] = s; }
        else        { flagF[r] = 1; flagF[cl] = 1; outFW[b * NRES + i] = -s; }
    }
}

// ---------------- hierarchical exclusive scan over flags (both sets at once) ----------------
__global__ __launch_bounds__(256) void k_scan1(const int* __restrict__ fc, const int* __restrict__ ff,
                                               int* __restrict__ bsC, int* __restrict__ bsF) {
    __shared__ int s1[256], s2[256];
    int t = threadIdx.x, v = blockIdx.x * 256 + t;
    s1[t] = fc[v]; s2[t] = ff[v];
    __syncthreads();
    for (int off = 128; off > 0; off >>= 1) {
        if (t < off) { s1[t] += s1[t + off]; s2[t] += s2[t + off]; }
        __syncthreads();
    }
    if (t == 0) { bsC[blockIdx.x] = s1[0]; bsF[blockIdx.x] = s2[0]; }
}

__global__ __launch_bounds__(256) void k_scan2(const int* __restrict__ bsC, const int* __restrict__ bsF,
                                               int* __restrict__ boC, int* __restrict__ boF,
                                               int* __restrict__ prefC, int* __restrict__ prefF) {
    __shared__ int s1[256], s2[256];
    int t = threadIdx.x;
    int v1 = bsC[t], v2 = bsF[t];
    s1[t] = v1; s2[t] = v2;
    __syncthreads();
    for (int off = 1; off < 256; off <<= 1) {
        int a1 = (t >= off) ? s1[t - off] : 0;
        int a2 = (t >= off) ? s2[t - off] : 0;
        __syncthreads();
        s1[t] += a1; s2[t] += a2;
        __syncthreads();
    }
    boC[t] = s1[t] - v1; boF[t] = s2[t] - v2;
    if (t == 255) { prefC[NN] = s1[255]; prefF[NN] = s2[255]; }
}

__global__ __launch_bounds__(256) void k_scan3(const int* __restrict__ fc, const int* __restrict__ ff,
                                               const int* __restrict__ boC, const int* __restrict__ boF,
                                               int* __restrict__ prefC, int* __restrict__ prefF) {
    __shared__ int s1[256], s2[256];
    int t = threadIdx.x, v = blockIdx.x * 256 + t;
    int f1 = fc[v], f2 = ff[v];
    s1[t] = f1; s2[t] = f2;
    __syncthreads();
    for (int off = 1; off < 256; off <<= 1) {
        int a1 = (t >= off) ? s1[t - off] : 0;
        int a2 = (t >= off) ? s2[t - off] : 0;
        __syncthreads();
        s1[t] += a1; s2[t] += a2;
        __syncthreads();
    }
    prefC[v] = boC[blockIdx.x] + s1[t] - f1;
    prefF[v] = boF[blockIdx.x] + s2[t] - f2;
}

// ---------------- combined scatter: both causal & conf, one h read ----------------
__global__ __launch_bounds__(256) void k_scatter2(const int* __restrict__ flagC, const int* __restrict__ prefC,
                                                  const int* __restrict__ flagF, const int* __restrict__ prefF,
                                                  const float* __restrict__ h,
                                                  float* __restrict__ outCX, float* __restrict__ outCB,
                                                  float* __restrict__ outFX, float* __restrict__ outFB) {
    int lane = threadIdx.x & 63;
    int i = blockIdx.x * 4 + (threadIdx.x >> 6);
    int c0 = lane << 2;
    int fC = flagC[i], fF = flagF[i];
    float4 hv = make_float4(0.f, 0.f, 0.f, 0.f);
    if (fC | fF) hv = *(const float4*)(h + (size_t)i * HIDC + c0);
    if (fC) {
        int p = prefC[i];
        *(float4*)(outCX + (size_t)p * HIDC + c0) = hv;
        if (lane == 0) outCB[p] = (float)(i >> 10);
    }
    if (fF) {
        int p = prefF[i];
        *(float4*)(outFX + (size_t)p * HIDC + c0) = hv;
        if (lane == 0) outFB[p] = (float)(i >> 10);
    }
    int nuC = prefC[NN], nuF = prefF[NN];
    float4 z = make_float4(0.f, 0.f, 0.f, 0.f);
    if (i >= nuC) { *(float4*)(outCX + (size_t)i * HIDC + c0) = z; if (lane == 0) outCB[i] = -1.0f; }
    if (i >= nuF) { *(float4*)(outFX + (size_t)i * HIDC + c0) = z; if (lane == 0) outFB[i] = -1.0f; }
}

// ---------------- relabeled edge indices (as floats) ----------------
__global__ void k_eirel(const int* __restrict__ perm, const int* __restrict__ row,
                        const int* __restrict__ col, const int* __restrict__ prefC,
                        const int* __restrict__ prefF,
                        float* __restrict__ outC, float* __restrict__ outF) {
    int g = blockIdx.x * blockDim.x + threadIdx.x;
    if (g >= EE) return;
    int b = g >> 13, jj = g & (EPB - 1);
    int ge = (b << 13) | perm[g];
    int r = row[ge], c = col[ge];
    if (jj < NRES) {
        int idx = b * NRES + jj;
        outC[idx] = (float)prefC[r];
        outC[BB * NRES + idx] = (float)prefC[c];
    } else {
        int idx = b * NRES + (jj - NRES);
        outF[idx] = (float)prefF[r];
        outF[BB * NRES + idx] = (float)prefF[c];
    }
}

extern "C" void kernel_launch(void* const* d_in, const int* in_sizes, int n_in,
                              void* d_out, int out_size, void* d_ws, size_t ws_size,
                              hipStream_t stream) {
    const float* x   = (const float*)d_in[0];
    const int*   ei  = (const int*)d_in[1];
    const int*   row = ei;
    const int*   col = ei + EE;
    const float* W11 = (const float*)d_in[3];
    const float* b11 = (const float*)d_in[4];
    const float* W12 = (const float*)d_in[5];
    const float* b12 = (const float*)d_in[6];
    const float* W21 = (const float*)d_in[7];
    const float* b21 = (const float*)d_in[8];
    const float* W22 = (const float*)d_in[9];
    const float* b22 = (const float*)d_in[10];
    const float* wsc = (const float*)d_in[11];
    const float* bsc = (const float*)d_in[12];

    float* out = (float*)d_out;

    // X buffer = causal_x output region (dead until final scatter)
    // usage: a1p (packed) -> h2 (fp32) -> h3p (packed)
    void* X = (void*)(out + O_CX);

    // workspace carve-up (256B aligned regions)
    char* w = (char*)d_ws;
    auto alloc = [&](size_t bytes) { char* p = w; w += (bytes + 255) & ~(size_t)255; return p; };
    void*  P         = (void*)alloc((size_t)NN * HIDC * 4);  // h1p -> a2p -> h (fp32)
    float* sSrc      = (float*)alloc((size_t)NN * 4);
    float* sDst      = (float*)alloc((size_t)NN * 4);
    int*   colSorted = (int*)alloc((size_t)EE * 4);
    int*   rowPtr    = (int*)alloc((size_t)(NN + 1) * 4);
    int*   perm      = (int*)alloc((size_t)EE * 4);
    unsigned long long* keys64 = (unsigned long long*)alloc((size_t)EE * 8);
    int*   flagC     = (int*)alloc((size_t)NN * 4);
    int*   flagF     = (int*)alloc((size_t)NN * 4);
    int*   prefC     = (int*)alloc((size_t)(NN + 1) * 4);
    int*   prefF     = (int*)alloc((size_t)(NN + 1) * 4);
    unsigned* Wtp    = (unsigned*)alloc((size_t)4 * 65536 * 4);
    int*   bsC       = (int*)alloc(256 * 4);
    int*   bsF       = (int*)alloc(256 * 4);
    int*   boC       = (int*)alloc(256 * 4);
    int*   boF       = (int*)alloc(256 * 4);

    float* esc = out + O_ES;  // edge scores written straight to output region

    hipLaunchKernelGGL(k_init, dim3(NN / 256), dim3(256), 0, stream, flagC, flagF, sSrc, sDst);
    hipLaunchKernelGGL(k_wsplit, dim3(1024), dim3(256), 0, stream, W11, W12, W21, W22, Wtp);
    hipLaunchKernelGGL(k_csr, dim3(BB), dim3(1024), 0, stream, row, col, rowPtr, colSorted);

    dim3 ggrid(NN / 128, 2), gblk(256);

    // layer 1
    hipLaunchKernelGGL(k_agg, dim3(NN / 4), dim3(256), 0, stream, x, x, colSorted, rowPtr, (unsigned*)X);
    k_gemm_mfma<0, 0><<<ggrid, gblk, 0, stream>>>((const unsigned*)X, Wtp + 0 * 65536, b11, P,
                                                  nullptr, nullptr, nullptr);                      // h1p
    k_gemm_mfma<1, 0><<<ggrid, gblk, 0, stream>>>((const unsigned*)P, Wtp + 1 * 65536, b12, X,
                                                  nullptr, nullptr, nullptr);                      // h2 fp32
    // layer 2
    hipLaunchKernelGGL(k_agg, dim3(NN / 4), dim3(256), 0, stream, (const float*)X, (const float*)X,
                       colSorted, rowPtr, (unsigned*)P);                                            // a2p
    k_gemm_mfma<0, 0><<<ggrid, gblk, 0, stream>>>((const unsigned*)P, Wtp + 2 * 65536, b21, X,
                                                  nullptr, nullptr, nullptr);                      // h3p
    k_gemm_mfma<1, 1><<<ggrid, gblk, 0, stream>>>((const unsigned*)X, Wtp + 3 * 65536, b22, P,
                                                  wsc, sSrc, sDst);                                // h fp32 + scores

    const float* h = (const float*)P;

    // edge scores
    hipLaunchKernelGGL(k_escore, dim3(EE / 256), dim3(256), 0, stream, row, col, sSrc, sDst, bsc, esc);

    // per-batch argsort (hybrid bitonic) + fused selection/flags
    hipLaunchKernelGGL(k_sortS1, dim3(BB * 2), dim3(512), 0, stream, esc, keys64);
    hipLaunchKernelGGL(k_sortS2, dim3(EE / 512), dim3(256), 0, stream, keys64);
    hipLaunchKernelGGL(k_sortS3, dim3(BB * 2), dim3(512), 0, stream, keys64, row, col, esc,
                       perm, flagC, flagF, out + O_CW, out + O_FW);

    // prefix sums for relabel
    hipLaunchKernelGGL(k_scan1, dim3(NN / 256), dim3(256), 0, stream, flagC, flagF, bsC, bsF);
    hipLaunchKernelGGL(k_scan2, dim3(1), dim3(256), 0, stream, bsC, bsF, boC, boF, prefC, prefF);
    hipLaunchKernelGGL(k_scan3, dim3(NN / 256), dim3(256), 0, stream, flagC, flagF, boC, boF, prefC, prefF);

    // outputs (causal scatter overwrites X region — X is dead by now)
    hipLaunchKernelGGL(k_scatter2, dim3(NN / 4), dim3(256), 0, stream, flagC, prefC, flagF, prefF, h,
                       out + O_CX, out + O_CB, out + O_FX, out + O_FB);
    hipLaunchKernelGGL(k_eirel, dim3(EE / 256), dim3(256), 0, stream, perm, row, col,
                       prefC, prefF, out + O_CEI, out + O_FEI);
}